// Round 10
// baseline (101.510 us; speedup 1.0000x reference)
//
#include <hip/hip_runtime.h>
#include <hip/hip_bf16.h>
#include <stdint.h>

#define M_DIM 32
#define K_DIM 8192
#define N_DIM 8192
#define NGROUPS 64
#define KSPLIT 16
#define KPART (K_DIM / KSPLIT)     // 512 k per part
#define GPART (NGROUPS / KSPLIT)   // 4 groups per part
#define BN 128

typedef __attribute__((ext_vector_type(8))) short short8;   // 8 bf16 (4 VGPRs)
typedef __attribute__((ext_vector_type(4))) float floatx4;  // MFMA acc

static __device__ __forceinline__ uint32_t bf16bits(float x) {
    union { __hip_bfloat16 h; uint16_t u; } cv;
    cv.h = __float2bfloat16(x);
    return (uint32_t)cv.u;
}
static __device__ __forceinline__ float bf16val(float x) {
    return __bfloat162float(__float2bfloat16(x));
}

// ---------------------------------------------------------------------------
// Main kernel (FUSED, R10): grid (N/128, KSPLIT=16) x 512 thr = 1024 blocks
// = 4/CU (LDS exactly 40 KB).  R9 post-mortem: staged-bytes cut was neutral;
// remaining suspects are prep-launch serialization + the atomic epilogue.
// R10: (1) no prep — each block converts its own fp32 A slice (coalesced
// lane-interleaved float4 + shfl_xor(1) pairing for the [0,4,1,5,2,6,3,7]
// octet permutation) into a STATIC 32 KB LDS image (A staged once, no
// per-group A restaging); rowsums R computed in-block (bx==0 writes 136*R
// to ws).  (2) no atomics — deterministic per-bz partials to ws; reduce
// kernel applies sum + R-correction + bias.  q staged per group by register
// bounce (coalesced global->VGPR one phase ahead, ds_write swizzled).
// ---------------------------------------------------------------------------
__global__ __launch_bounds__(512, 4) void
MarlinQuantLinear_68556267979256_kernel(const int* __restrict__ qw,
                                        const float* __restrict__ scales,
                                        const float* __restrict__ A,
                                        float* __restrict__ P,     // [16][32][8192]
                                        float* __restrict__ Rws) { // [32][64] 136*R
    __shared__ uint32_t abuf[32 * 256];  // 32 KB: 32 rows x 64 swizzled 16B chunks
    __shared__ uint32_t qbuf[16 * 128];  //  8 KB: 16 rows x 128 dwords (swizzled)

    const int bx = blockIdx.x;            // n-tile block
    const int bz = blockIdx.y;            // k-split part
    const int nbase = bx * BN;
    const int kbase = bz * KPART;
    const int gbase = bz * GPART;
    const int qrow0 = bz * (KPART / 8);   // 64 packed q-rows per part

    const int tid = threadIdx.x;
    const int w = tid >> 6;
    const int lane = tid & 63;
    const int quad = lane >> 4;
    const int l16 = lane & 15;
    const int mtile = w & 1;
    const int nt0 = (w >> 1) * 2;
    const int ncol0 = nbase + nt0 * 16 + l16;
    const int ncol1 = ncol0 + 16;
    const int arow = mtile * 16 + l16;

    // ---- q g=0 prefetch (coalesced): thread -> (row qr, 16B chunk qc) ----
    const int qr = tid >> 5, qc = tid & 31;
    const int* qsrc = qw + (size_t)(qrow0 + qr) * N_DIM + nbase + qc * 4;
    uint4 qreg = *(const uint4*)qsrc;

    // ---- scales prefetch ----
    const float* scol = scales + (size_t)gbase * N_DIM;
    float s0[GPART], s1[GPART];
#pragma unroll
    for (int g = 0; g < GPART; g++) {
        s0[g] = scol[g * N_DIM + ncol0];
        s1[g] = scol[g * N_DIM + ncol1];
    }

    // ---- A slice: fp32 -> bf16 -> LDS (one-time) ----
    // thread(row srow, seg sseg): owns float4 indices sseg+16j (j=0..7) of the
    // row's 128-float4 slice -> lane-interleaved => fully coalesced loads.
    const int srow = tid >> 4, sseg = tid & 15;
    const float4* af4 = (const float4*)(A + (size_t)srow * K_DIM + kbase);
    float4 f4[8];
#pragma unroll
    for (int j = 0; j < 8; j++) f4[j] = af4[sseg + 16 * j];

    // convert own values; accumulate per-group rowsum partials (2 f4 = 8
    // values per group per thread: j=2g,2g+1)
    uint32_t own[8][4];
    float rpart[GPART];
#pragma unroll
    for (int g = 0; g < GPART; g++) rpart[g] = 0.f;
#pragma unroll
    for (int j = 0; j < 8; j++) {
        own[j][0] = bf16bits(f4[j].x); own[j][1] = bf16bits(f4[j].y);
        own[j][2] = bf16bits(f4[j].z); own[j][3] = bf16bits(f4[j].w);
        rpart[j >> 1] += bf16val(f4[j].x) + bf16val(f4[j].y)
                       + bf16val(f4[j].z) + bf16val(f4[j].w);
    }
    // pair halves: even sseg holds b0..b3 of octet o=(sseg>>1)+8j, odd holds
    // b4..b7 -> exchange via adjacent-lane shuffle, even lane packs+writes.
#pragma unroll
    for (int j = 0; j < 8; j++) {
        float nx = __shfl_xor(f4[j].x, 1), ny = __shfl_xor(f4[j].y, 1);
        float nz = __shfl_xor(f4[j].z, 1), nw = __shfl_xor(f4[j].w, 1);
        if ((sseg & 1) == 0) {
            uint32_t w0 = own[j][0] | (bf16bits(nx) << 16);  // b0|b4
            uint32_t w1 = own[j][1] | (bf16bits(ny) << 16);  // b1|b5
            uint32_t w2 = own[j][2] | (bf16bits(nz) << 16);  // b2|b6
            uint32_t w3 = own[j][3] | (bf16bits(nw) << 16);  // b3|b7
            const int o = (sseg >> 1) + 8 * j;               // octet 0..63
            const int pos = o ^ (srow & 15);                 // XOR swizzle
            *(uint4*)&abuf[srow * 256 + pos * 4] = make_uint4(w0, w1, w2, w3);
        }
    }
    // reduce rowsums over the row's 16 segs (lanes (srow%4)*16 + seg)
#pragma unroll
    for (int g = 0; g < GPART; g++) {
#pragma unroll
        for (int off = 1; off < 16; off <<= 1)
            rpart[g] += __shfl_xor(rpart[g], off);
    }
    if (bx == 0 && sseg == 0) {
#pragma unroll
        for (int g = 0; g < GPART; g++)
            Rws[srow * NGROUPS + gbase + g] = 136.0f * rpart[g];
    }

    // stage q(0) into LDS (qreg loaded long ago), prefetch q(1)
    const int qdst = qr * 128 + (qc ^ ((qr & 1) << 2)) * 4;  // swizzled chunk
    *(uint4*)&qbuf[qdst] = qreg;
    qreg = *(const uint4*)(qsrc + (size_t)16 * N_DIM);
    __syncthreads();    // abuf + qbuf(0) visible

    floatx4 C0 = {0.f, 0.f, 0.f, 0.f};
    floatx4 C1 = {0.f, 0.f, 0.f, 0.f};

#pragma unroll
    for (int g = 0; g < GPART; g++) {
        floatx4 acc0 = {0.f, 0.f, 0.f, 0.f};
        floatx4 acc1 = {0.f, 0.f, 0.f, 0.f};
#pragma unroll
        for (int t = 0; t < 4; t++) {
            const int qrow = (t * 4 + quad) * 128;
            const int swz = (quad & 1) << 4;
            const uint32_t qA = qbuf[qrow + (ncol0 - nbase ^ swz)];
            const uint32_t qB = qbuf[qrow + (ncol1 - nbase ^ swz)];
            const int c = g * 16 + t * 4 + quad;
            const short8 fa = *(const short8*)
                &abuf[arow * 256 + (c ^ (arow & 15)) * 4];
            union { uint32_t u[4]; short8 v; } fb;
            fb.u[0] = ( qA        & 0x000F000Fu) | 0x43004300u;  // k0,k4
            fb.u[1] = ((qA >> 4)  & 0x000F000Fu) | 0x43004300u;  // k1,k5
            fb.u[2] = ((qA >> 8)  & 0x000F000Fu) | 0x43004300u;  // k2,k6
            fb.u[3] = ((qA >> 12) & 0x000F000Fu) | 0x43004300u;  // k3,k7
            acc0 = __builtin_amdgcn_mfma_f32_16x16x32_bf16(fa, fb.v, acc0, 0, 0, 0);
            fb.u[0] = ( qB        & 0x000F000Fu) | 0x43004300u;
            fb.u[1] = ((qB >> 4)  & 0x000F000Fu) | 0x43004300u;
            fb.u[2] = ((qB >> 8)  & 0x000F000Fu) | 0x43004300u;
            fb.u[3] = ((qB >> 12) & 0x000F000Fu) | 0x43004300u;
            acc1 = __builtin_amdgcn_mfma_f32_16x16x32_bf16(fa, fb.v, acc1, 0, 0, 0);
        }
#pragma unroll
        for (int r = 0; r < 4; r++) {
            C0[r] = fmaf(s0[g], acc0[r], C0[r]);
            C1[r] = fmaf(s1[g], acc1[r], C1[r]);
        }
        if (g + 1 < GPART) {
            __syncthreads();                     // all done reading qbuf(g)
            *(uint4*)&qbuf[qdst] = qreg;         // qreg in flight one phase
            if (g + 2 < GPART)
                qreg = *(const uint4*)(qsrc + (size_t)(g + 2) * 16 * N_DIM);
            __syncthreads();                     // qbuf(g+1) visible
        }
    }

    // deterministic partials (no atomics): P[bz][m][n]
#pragma unroll
    for (int r = 0; r < 4; r++) {
        const int m = mtile * 16 + quad * 4 + r;   // C/D row = quad*4 + reg
        P[((size_t)bz * 32 + m) * N_DIM + ncol0] = C0[r];
        P[((size_t)bz * 32 + m) * N_DIM + ncol1] = C1[r];
    }
}

// ---------------------------------------------------------------------------
// Reduce: out[m][n] = bias[n] + sum_bz P[bz][m][n] - sum_g s[g][n]*(136R[m][g])
// grid 128 x 256: block owns a 64-col strip, all 32 m.
// ---------------------------------------------------------------------------
__global__ void marlin_reduce_kernel(const float* __restrict__ P,
                                     const float* __restrict__ Rws,
                                     const float* __restrict__ scales,
                                     const float* __restrict__ bias,
                                     float* __restrict__ out) {
    __shared__ float s_l[64 * 64];   // [g][c] 16 KB
    __shared__ float r_l[32 * 64];   // [m][g]  8 KB (already x136)
    const int tid = threadIdx.x;
    const int nblk = blockIdx.x * 64;
#pragma unroll
    for (int i = 0; i < 16; i++) {
        const int idx = i * 256 + tid;
        s_l[idx] = scales[(size_t)(idx >> 6) * N_DIM + nblk + (idx & 63)];
    }
#pragma unroll
    for (int i = 0; i < 8; i++) {
        const int idx = i * 256 + tid;
        r_l[idx] = Rws[idx];
    }
    __syncthreads();

    const int c = tid & 63;
    const int mq = tid >> 6;         // 0..3
    const int n = nblk + c;
    const float bv = bias[n];
#pragma unroll
    for (int mi = 0; mi < 8; mi++) {
        const int m = mq * 8 + mi;
        float acc = bv;
#pragma unroll
        for (int bz = 0; bz < KSPLIT; bz++)
            acc += P[((size_t)bz * 32 + m) * N_DIM + n];
        float corr = 0.f;
#pragma unroll
        for (int g = 0; g < NGROUPS; g++)
            corr = fmaf(s_l[g * 64 + c], r_l[m * 64 + g], corr);
        out[(size_t)m * N_DIM + n] = acc - corr;
    }
}

extern "C" void kernel_launch(void* const* d_in, const int* in_sizes, int n_in,
                              void* d_out, int out_size, void* d_ws, size_t ws_size,
                              hipStream_t stream) {
    const float* A      = (const float*)d_in[0];
    const int*   qw     = (const int*)d_in[1];
    const float* scales = (const float*)d_in[2];
    const float* bias   = (const float*)d_in[3];
    float* out = (float*)d_out;

    float* P   = (float*)d_ws;                                    // 16 MB
    float* Rws = (float*)((char*)d_ws + (size_t)16 * 1024 * 1024); // 8 KB

    MarlinQuantLinear_68556267979256_kernel<<<dim3(N_DIM / BN, KSPLIT), 512, 0, stream>>>(
        qw, scales, A, P, Rws);
    marlin_reduce_kernel<<<128, 256, 0, stream>>>(P, Rws, scales, bias, out);
}